// Round 11
// baseline (202.522 us; speedup 1.0000x reference)
//
#include <hip/hip_runtime.h>
#include <math.h>

#define B_ 8
#define S_ 1024
#define D_ 1024
constexpr int BS = B_ * S_;

typedef short bf16x8 __attribute__((ext_vector_type(8)));
typedef float f32x4 __attribute__((ext_vector_type(4)));

__device__ __forceinline__ unsigned short f2bf(float f) {
    unsigned int u = __float_as_uint(f);
    u += 0x7fffu + ((u >> 16) & 1u);
    return (unsigned short)(u >> 16);
}
__device__ __forceinline__ float bf2f(unsigned short h) {
    return __uint_as_float(((unsigned int)h) << 16);
}

__device__ __forceinline__ float block_reduce_sum(float val, float* sh) {
    int tid = threadIdx.x;
    int lane = tid & 63, w = tid >> 6;
    #pragma unroll
    for (int off = 32; off > 0; off >>= 1) val += __shfl_down(val, off, 64);
    if (lane == 0) sh[w] = val;
    __syncthreads();
    int nw = blockDim.x >> 6;
    float total = 0.f;
    for (int i = 0; i < nw; i++) total += sh[i];
    __syncthreads();
    return total;
}

__device__ __forceinline__ float wave_reduce_sum(float v) {
    #pragma unroll
    for (int off = 32; off > 0; off >>= 1) v += __shfl_xor(v, off, 64);
    return v;
}

// ---- prep: transpose-convert Wq,Wk -> bf16; u,v GEMV (no atomics); c0 ------
__global__ void prep_kernel(const float* __restrict__ Wq, const float* __restrict__ Wk,
                            const float* __restrict__ bq, const float* __restrict__ bk,
                            unsigned short* __restrict__ Wqt,
                            unsigned short* __restrict__ Wkt,
                            float* __restrict__ u, float* __restrict__ v,
                            float* __restrict__ c0) {
    int bid = blockIdx.x;
    int tid = threadIdx.x;         // 256
    if (bid < 2048) {
        __shared__ float t[32][33];
        const float* in = (bid < 1024) ? Wq : Wk;
        unsigned short* out = (bid < 1024) ? Wqt : Wkt;
        int bb = bid & 1023;
        int bx = (bb & 31) * 32, by = (bb >> 5) * 32;
        int tx = tid & 31, ty = tid >> 5;    // 32 x 8
        #pragma unroll
        for (int i = 0; i < 32; i += 8)
            t[ty + i][tx] = in[(size_t)(by + ty + i) * D_ + bx + tx];
        __syncthreads();
        #pragma unroll
        for (int i = 0; i < 32; i += 8)
            out[(size_t)(bx + ty + i) * D_ + by + tx] = f2bf(t[tx][ty + i]);
    } else if (bid < 2112) {
        // u[c] = sum_d Wk[d][c]*bq[d]; v[c] = sum_d Wq[d][c]*bk[d]
        __shared__ float shu[16][17], shv[16][17];
        int g = bid - 2048;          // 0..63
        int cbase = g * 16;
        int cc = tid & 15, dg = tid >> 4;   // 16 cols x 16 d-groups
        float ua = 0.f, va = 0.f;
        for (int d = dg; d < D_; d += 16) {
            ua += Wk[(size_t)d * D_ + cbase + cc] * bq[d];
            va += Wq[(size_t)d * D_ + cbase + cc] * bk[d];
        }
        shu[dg][cc] = ua; shv[dg][cc] = va;
        __syncthreads();
        if (tid < 16) {
            float su_ = 0.f, sv_ = 0.f;
            #pragma unroll
            for (int k = 0; k < 16; k++) { su_ += shu[k][tid]; sv_ += shv[k][tid]; }
            u[cbase + tid] = su_;
            v[cbase + tid] = sv_;
        }
    } else {
        // c0 = sum_d bq[d]*bk[d]
        __shared__ float sh2[4];
        float p = 0.f;
        #pragma unroll
        for (int i = 0; i < 4; i++) {
            int d = tid + i * 256;
            p += bq[d] * bk[d];
        }
        float tot = block_reduce_sum(p, sh2);
        if (tid == 0) c0[0] = tot;
    }
}

// ---- MERGED: LayerNorm (wave-per-row) + Mt GEMM (2-phase 64x64) ------------
__global__ __launch_bounds__(256) void ln_bt64(
    const float* __restrict__ ctx,
    const float* __restrict__ ln_a, const float* __restrict__ ln_b,
    const float* __restrict__ u, const float* __restrict__ v,
    unsigned short* __restrict__ xb,
    float* __restrict__ au, float* __restrict__ av,
    const unsigned short* __restrict__ A,   // Wkt
    const unsigned short* __restrict__ Bt,  // Wqt
    unsigned short* __restrict__ C) {       // Mt
    __shared__ __align__(16) unsigned short smem[16384];  // 32 KB (bt64 only)
    const int bid = blockIdx.x;
    const int tid = threadIdx.x;
    if (bid < 256) {
        const int wave = tid >> 6, lane = tid & 63;
        const int bm = (bid >> 4) * 64, bn = (bid & 15) * 64;
        const int lrow8 = lane >> 3;
        const int pchunk = lane & 7;
        const int m_lane = lane & 15, quad = lane >> 4;
        const int wr = wave >> 1, wc = wave & 1;

        f32x4 acc[2][2] = {};

        auto stage = [&](int buf, int k0) {
            unsigned short* As = smem + buf * 8192;
            unsigned short* Bs = As + 4096;
            #pragma unroll
            for (int c = 0; c < 2; c++) {
                int row = wave * 16 + c * 8 + lrow8;
                int gchunk = pchunk ^ (row & 7);
                const unsigned short* gpA = A + (size_t)(bm + row) * D_ + k0 + gchunk * 8;
                const unsigned short* gpB = Bt + (size_t)(bn + row) * D_ + k0 + gchunk * 8;
                __builtin_amdgcn_global_load_lds(
                    (const __attribute__((address_space(1))) void*)gpA,
                    (__attribute__((address_space(3))) void*)(As + (wave * 16 + c * 8) * 64),
                    16, 0, 0);
                __builtin_amdgcn_global_load_lds(
                    (const __attribute__((address_space(1))) void*)gpB,
                    (__attribute__((address_space(3))) void*)(Bs + (wave * 16 + c * 8) * 64),
                    16, 0, 0);
            }
        };

        const int nt = D_ >> 6;
        stage(0, 0);
        __syncthreads();
        int cur = 0;
        for (int t = 0; t < nt; ++t) {
            if (t < nt - 1) stage(cur ^ 1, (t + 1) * 64);
            const unsigned short* As = smem + cur * 8192;
            const unsigned short* Bs = As + 4096;
            #pragma unroll
            for (int kk = 0; kk < 2; kk++) {
                bf16x8 af[2], bfr[2];
                #pragma unroll
                for (int i = 0; i < 2; i++) {
                    int row = wr * 32 + i * 16 + m_lane;
                    int lchunk = kk * 4 + quad;
                    af[i] = *(const bf16x8*)(As + row * 64 + (lchunk ^ (row & 7)) * 8);
                }
                #pragma unroll
                for (int j = 0; j < 2; j++) {
                    int row = wc * 32 + j * 16 + m_lane;
                    int lchunk = kk * 4 + quad;
                    bfr[j] = *(const bf16x8*)(Bs + row * 64 + (lchunk ^ (row & 7)) * 8);
                }
                #pragma unroll
                for (int i = 0; i < 2; i++)
                    #pragma unroll
                    for (int j = 0; j < 2; j++)
                        acc[i][j] = __builtin_amdgcn_mfma_f32_16x16x32_bf16(
                            af[i], bfr[j], acc[i][j], 0, 0, 0);
            }
            __syncthreads();
            cur ^= 1;
        }
        #pragma unroll
        for (int i = 0; i < 2; i++)
            #pragma unroll
            for (int j = 0; j < 2; j++)
                #pragma unroll
                for (int r = 0; r < 4; r++) {
                    int row = bm + wr * 32 + i * 16 + quad * 4 + r;
                    int col = bn + wc * 32 + j * 16 + m_lane;
                    C[(size_t)row * D_ + col] = f2bf(acc[i][j][r]);
                }
    } else {
        // ---- LayerNorm branch: wave-per-row, zero barriers ----
        int wid = tid >> 6, lane = tid & 63;
        int r = (bid - 256) * 4 + wid;
        const float* row = ctx + (size_t)r * D_;
        float4 x[4];
        #pragma unroll
        for (int j = 0; j < 4; j++)
            x[j] = *(const float4*)(row + lane * 4 + j * 256);
        float s = 0.f;
        #pragma unroll
        for (int j = 0; j < 4; j++) s += x[j].x + x[j].y + x[j].z + x[j].w;
        s = wave_reduce_sum(s);
        float mean = s * (1.0f / D_);
        float sq = 0.f;
        #pragma unroll
        for (int j = 0; j < 4; j++) {
            float dx = x[j].x - mean, dy = x[j].y - mean;
            float dz = x[j].z - mean, dw = x[j].w - mean;
            sq += dx * dx + dy * dy + dz * dz + dw * dw;
        }
        sq = wave_reduce_sum(sq);
        float var = sq * (1.0f / (D_ - 1));
        float inv = 1.0f / (sqrtf(var) + 1e-6f);
        float pu = 0.f, pv = 0.f;
        #pragma unroll
        for (int j = 0; j < 4; j++) {
            int d0 = lane * 4 + j * 256;
            float4 a4 = *(const float4*)(ln_a + d0);
            float4 b4 = *(const float4*)(ln_b + d0);
            float y0 = a4.x * (x[j].x - mean) * inv + b4.x;
            float y1 = a4.y * (x[j].y - mean) * inv + b4.y;
            float y2 = a4.z * (x[j].z - mean) * inv + b4.z;
            float y3 = a4.w * (x[j].w - mean) * inv + b4.w;
            ushort4 o;
            o.x = f2bf(y0); o.y = f2bf(y1); o.z = f2bf(y2); o.w = f2bf(y3);
            *(ushort4*)(xb + (size_t)r * D_ + d0) = o;
            float4 u4 = *(const float4*)(u + d0);
            float4 v4 = *(const float4*)(v + d0);
            pu += u4.x * y0 + u4.y * y1 + u4.z * y2 + u4.w * y3;
            pv += v4.x * y0 + v4.y * y1 + v4.z * y2 + v4.w * y3;
        }
        pu = wave_reduce_sum(pu);
        pv = wave_reduce_sum(pv);
        if (lane == 0) { au[r] = pu; av[r] = pv; }
    }
}

// ---- MFMA GEMM 128x128 tile, 2-PHASE double-buffered pipeline --------------
__device__ __forceinline__ int xs_idx(int row, int col) {
    return row * 128 + (((col >> 3) ^ (row & 7)) << 3) + (col & 7);
}

__global__ __launch_bounds__(256) void gemm_fused(
    const unsigned short* __restrict__ A,   // Xb [BS][D]
    const unsigned short* __restrict__ Bt,  // Mt [D][D]
    float* __restrict__ ydu_part, float* __restrict__ ydd_part,
    int M, int N, int K) {
    __shared__ __align__(16) unsigned short smem[32768];  // 65536 B
    const int tid = threadIdx.x;
    const int wave = tid >> 6, lane = tid & 63;
    const int bid = blockIdx.x;
    const int bm = (bid & 63) * 128, bn = (bid >> 6) * 128;
    const int lrow8 = lane >> 3;             // 0..7
    const int pchunk = lane & 7;
    const int m_lane = lane & 15, quad = lane >> 4;
    const int wr = wave >> 1, wc = wave & 1; // wave's 64x64 quadrant

    f32x4 acc[4][4] = {};                    // rows wr*64+i*16, cols wc*64+j*16

    auto stage = [&](int buf, int k0) {
        unsigned short* As = smem + buf * 16384;
        unsigned short* Bs = As + 8192;
        #pragma unroll
        for (int c = 0; c < 4; c++) {
            int row = wave * 32 + c * 8 + lrow8;
            int gchunk = pchunk ^ (row & 7);
            const unsigned short* gpA = A + (size_t)(bm + row) * K + k0 + gchunk * 8;
            __builtin_amdgcn_global_load_lds(
                (const __attribute__((address_space(1))) void*)gpA,
                (__attribute__((address_space(3))) void*)(As + (wave * 32 + c * 8) * 64),
                16, 0, 0);
            const unsigned short* gpB = Bt + (size_t)(bn + row) * K + k0 + gchunk * 8;
            __builtin_amdgcn_global_load_lds(
                (const __attribute__((address_space(1))) void*)gpB,
                (__attribute__((address_space(3))) void*)(Bs + (wave * 32 + c * 8) * 64),
                16, 0, 0);
        }
    };

    const int nt = K >> 6;                   // 16 K-steps
    stage(0, 0);
    __syncthreads();                          // drain prologue loads
    int cur = 0;
    for (int t = 0; t < nt; ++t) {
        if (t < nt - 1) stage(cur ^ 1, (t + 1) * 64);   // prefetch next tile
        const unsigned short* As = smem + cur * 16384;
        const unsigned short* Bs = As + 8192;
        #pragma unroll
        for (int kk = 0; kk < 2; kk++) {
            bf16x8 af[4], bfr[4];
            #pragma unroll
            for (int i = 0; i < 4; i++) {
                int row = wr * 64 + i * 16 + m_lane;
                int lchunk = kk * 4 + quad;
                af[i] = *(const bf16x8*)(As + row * 64 + (lchunk ^ (row & 7)) * 8);
            }
            #pragma unroll
            for (int j = 0; j < 4; j++) {
                int row = wc * 64 + j * 16 + m_lane;
                int lchunk = kk * 4 + quad;
                bfr[j] = *(const bf16x8*)(Bs + row * 64 + (lchunk ^ (row & 7)) * 8);
            }
            #pragma unroll
            for (int i = 0; i < 4; i++)
                #pragma unroll
                for (int j = 0; j < 4; j++)
                    acc[i][j] = __builtin_amdgcn_mfma_f32_16x16x32_bf16(
                        af[i], bfr[j], acc[i][j], 0, 0, 0);
        }
        __syncthreads();   // vmcnt(0)+lgkmcnt(0)+barrier: next buf ready, cur buf free
        cur ^= 1;
    }

    // ---- epilogue: stage X tile [128][128] via global_load_lds -------------
    unsigned short* Xs = smem;               // [128][128] linear u16 = 32 KB
    #pragma unroll
    for (int it = 0; it < 8; it++) {
        int c = it * 256 + wave * 64 + lane; // chunk id, 2048 total
        int lr = c >> 4;                     // 0..127
        int ch = c & 15;                     // 0..15
        int gch = ch ^ (lr & 7);             // source swizzle (involution)
        const unsigned short* gp = A + (size_t)(bm + lr) * K + bn + gch * 8;
        __builtin_amdgcn_global_load_lds(
            (const __attribute__((address_space(1))) void*)gp,
            (__attribute__((address_space(3))) void*)(Xs + (size_t)(it * 256 + wave * 64) * 8),
            16, 0, 0);
    }
    __syncthreads();

    const int part = (bid >> 6) * 2 + wc;    // 0..15, unique per (ntile, wc)
    #pragma unroll
    for (int i = 0; i < 4; i++) {
        #pragma unroll
        for (int r = 0; r < 4; r++) {
            int lrow = wr * 64 + i * 16 + quad * 4 + r;   // 0..127
            int row = bm + lrow;
            int s = row & (S_ - 1);
            bool hu = (s < S_ - 1), hd = (s > 0);
            float pu = 0.f, pd = 0.f;
            #pragma unroll
            for (int j = 0; j < 4; j++) {
                int lc = wc * 64 + j * 16 + m_lane;
                float a = acc[i][j][r];
                if (hu) {
                    float xu = (lrow < 127) ? bf2f(Xs[xs_idx(lrow + 1, lc)])
                                            : bf2f(A[(size_t)(row + 1) * K + bn + lc]);
                    pu += a * xu;
                }
                if (hd) {
                    float xd = (lrow > 0) ? bf2f(Xs[xs_idx(lrow - 1, lc)])
                                          : bf2f(A[(size_t)(row - 1) * K + bn + lc]);
                    pd += a * xd;
                }
            }
            #pragma unroll
            for (int off = 1; off < 16; off <<= 1) {
                pu += __shfl_xor(pu, off, 64);
                pd += __shfl_xor(pd, off, 64);
            }
            if (m_lane == 0) {
                ydu_part[(size_t)part * BS + row] = pu;
                ydd_part[(size_t)part * BS + row] = pd;
            }
        }
    }
}

// ---- WIDE banded softmax: one thread per row, full-GPU parallel ------------
__global__ __launch_bounds__(128) void softmax_wide(
    const float* __restrict__ ydu_part, const float* __restrict__ ydd_part,
    const float* __restrict__ au, const float* __restrict__ av,
    const float* __restrict__ c0p, const int* __restrict__ eos,
    float* __restrict__ Pup, float* __restrict__ Pdn, float* __restrict__ bg) {
    int r = blockIdx.x * 128 + threadIdx.x;   // 0..8191
    int b = r >> 10, t = r & (S_ - 1);
    float c0 = *c0p;
    const float inv_d = 1.0f / D_;
    bool mu = false, md = false;
    float su = 0.f, sd = 0.f;
    if (t < S_ - 1) {
        mu = eos[(size_t)b * S_ * S_ + (size_t)t * S_ + (t + 1)] != 0;
        float s_ = 0.f;
        #pragma unroll
        for (int j = 0; j < 16; j++) s_ += ydu_part[(size_t)j * BS + r];
        su = (s_ + av[r] + au[r + 1] + c0) * inv_d;
    }
    if (t > 0) {
        md = eos[(size_t)b * S_ * S_ + (size_t)t * S_ + (t - 1)] != 0;
        float s_ = 0.f;
        #pragma unroll
        for (int j = 0; j < 16; j++) s_ += ydd_part[(size_t)j * BS + r];
        sd = (s_ + av[r] + au[r - 1] + c0) * inv_d;
    }
    float pu, pd, pb;
    if (mu && md) {
        float m = fmaxf(su, sd);
        float eu = expf(su - m), ed = expf(sd - m);
        float inv = 1.0f / (eu + ed);
        pu = eu * inv; pd = ed * inv; pb = 0.f;
    } else if (mu) { pu = 1.f; pd = 0.f; pb = 0.f; }
    else if (md)   { pu = 0.f; pd = 1.f; pb = 0.f; }
    else           { pu = pd = pb = 1.0f / S_; }
    Pup[r] = pu; Pdn[r] = pd; bg[r] = pb;
}

// ---- f64 prefix scan (per-batch serial part only; inputs coalesced) --------
__global__ __launch_bounds__(1024) void prefix_scan(
    const float* __restrict__ Pup, const float* __restrict__ Pdn,
    double* __restrict__ C) {
    __shared__ double wsum[16];
    int b = blockIdx.x;
    int t = threadIdx.x;           // 0..1023
    int r = b * S_ + t;
    double l = 0.0;
    if (t < S_ - 1) {
        float p = sqrtf(Pup[r] * Pdn[r + 1] + 1e-9f) + 1e-9f;
        l = log((double)p);
    }
    int lane = t & 63, w = t >> 6;
    double vv = l;
    #pragma unroll
    for (int off = 1; off < 64; off <<= 1) {
        double o = __shfl_up(vv, off, 64);
        if (lane >= off) vv += o;
    }
    if (lane == 63) wsum[w] = vv;
    __syncthreads();
    if (t == 0) {
        double acc = 0.0;
        #pragma unroll
        for (int i = 0; i < 16; i++) { double x = wsum[i]; wsum[i] = acc; acc += x; }
    }
    __syncthreads();
    vv += wsum[w];
    size_t base = (size_t)b * S_;
    if (t == 0) C[base] = 0.0;
    if (t < S_ - 1) C[base + t + 1] = vv;
}

// ---- final outputs: g and neibor -------------------------------------------
__global__ void write_out(const float* __restrict__ Pup, const float* __restrict__ Pdn,
                          const float* __restrict__ bg, const double* __restrict__ C,
                          float* __restrict__ out) {
    int r = blockIdx.x;
    int b = r >> 10, s = r & (S_ - 1);
    size_t rowbase = (size_t)r * S_;
    size_t bb = (size_t)b * S_;
    float pu_s = (s < S_ - 1) ? Pup[r] : 0.f;
    float pd_s = (s > 0) ? Pdn[r] : 0.f;
    float bg_s = bg[r];
    double C_s = C[r];
    int t0 = threadIdx.x * 4;
    float* gp = out;
    float* np = out + (size_t)B_ * S_ * S_;
    float4 bgv = *(const float4*)(bg + bb + t0);
    float4 gv, nv;
    #pragma unroll
    for (int j = 0; j < 4; j++) {
        int t = t0 + j;
        float P_st = (t == s + 1) ? pu_s : ((t == s - 1) ? pd_s : bg_s);
        float P_ts;
        if (t == s - 1)      P_ts = Pup[bb + t];
        else if (t == s + 1) P_ts = Pdn[bb + t];
        else                 P_ts = ((const float*)&bgv)[j];
        float neib = sqrtf(P_st * P_ts + 1e-9f);
        float g;
        if (t == s) {
            g = neib;
        } else {
            double diff = (t > s) ? (C[bb + t] - C_s) : (C_s - C[bb + t]);
            g = expf((float)diff) + 1e-9f;
        }
        ((float*)&gv)[j] = g;
        ((float*)&nv)[j] = neib;
    }
    *(float4*)(gp + rowbase + t0) = gv;
    *(float4*)(np + rowbase + t0) = nv;
}

// ---- launcher: 6 dispatches --------------------------------------------------
extern "C" void kernel_launch(void* const* d_in, const int* in_sizes, int n_in,
                              void* d_out, int out_size, void* d_ws, size_t ws_size,
                              hipStream_t stream) {
    const float* ctx  = (const float*)d_in[0];
    const int*   eos  = (const int*)d_in[1];
    const float* Wq   = (const float*)d_in[2];
    const float* bq   = (const float*)d_in[3];
    const float* Wk   = (const float*)d_in[4];
    const float* bk   = (const float*)d_in[5];
    const float* ln_a = (const float*)d_in[6];
    const float* ln_b = (const float*)d_in[7];
    float* out = (float*)d_out;

    char* ws = (char*)d_ws;
    size_t off = 0;
    auto alloc = [&](size_t bytes) {
        void* p = ws + off;
        off += (bytes + 255) & ~(size_t)255;
        return p;
    };
    unsigned short* Xb  = (unsigned short*)alloc((size_t)BS * D_ * 2);
    unsigned short* Wqt = (unsigned short*)alloc((size_t)D_ * D_ * 2);
    unsigned short* Wkt = (unsigned short*)alloc((size_t)D_ * D_ * 2);
    unsigned short* Mt  = (unsigned short*)alloc((size_t)D_ * D_ * 2);
    float*  ydu_part = (float*)alloc((size_t)16 * BS * 4);
    float*  ydd_part = (float*)alloc((size_t)16 * BS * 4);
    float*  u   = (float*)alloc(D_ * 4);
    float*  v   = (float*)alloc(D_ * 4);
    float*  c0  = (float*)alloc(4);
    float*  au  = (float*)alloc(BS * 4);
    float*  av  = (float*)alloc(BS * 4);
    float*  Pup = (float*)alloc(BS * 4);
    float*  Pdn = (float*)alloc(BS * 4);
    float*  bg  = (float*)alloc(BS * 4);
    double* Cp  = (double*)alloc(BS * 8);

    // 1. prep: transpose Wq/Wk -> bf16; u,v GEMV (direct store); c0
    prep_kernel<<<2113, 256, 0, stream>>>(Wq, Wk, bq, bk, Wqt, Wkt, u, v, c0);
    // 2. merged: Mt GEMM (256 blocks) + LayerNorm (2048 blocks)
    ln_bt64<<<2304, 256, 0, stream>>>(ctx, ln_a, ln_b, u, v, Xb, au, av,
                                      Wkt, Wqt, Mt);
    // 3. fused: Y = Xb Mt^T + banded dots -> 16 partial buffers (no atomics)
    gemm_fused<<<512, 256, 0, stream>>>(Xb, Mt, ydu_part, ydd_part, BS, D_, D_);
    // 4. wide banded softmax (full-GPU parallel eos loads + partial sums)
    softmax_wide<<<64, 128, 0, stream>>>(ydu_part, ydd_part, au, av, c0, eos,
                                         Pup, Pdn, bg);
    // 5. per-batch f64 prefix scan (serial part only, coalesced inputs)
    prefix_scan<<<B_, 1024, 0, stream>>>(Pup, Pdn, Cp);
    // 6. outputs
    write_out<<<BS, 256, 0, stream>>>(Pup, Pdn, bg, Cp, out);
}

// Round 12
// 196.714 us; speedup vs baseline: 1.0295x; 1.0295x over previous
//
#include <hip/hip_runtime.h>
#include <math.h>

#define B_ 8
#define S_ 1024
#define D_ 1024
constexpr int BS = B_ * S_;

typedef short bf16x8 __attribute__((ext_vector_type(8)));
typedef float f32x4 __attribute__((ext_vector_type(4)));

__device__ __forceinline__ unsigned short f2bf(float f) {
    unsigned int u = __float_as_uint(f);
    u += 0x7fffu + ((u >> 16) & 1u);
    return (unsigned short)(u >> 16);
}
__device__ __forceinline__ float bf2f(unsigned short h) {
    return __uint_as_float(((unsigned int)h) << 16);
}

__device__ __forceinline__ float block_reduce_sum(float val, float* sh) {
    int tid = threadIdx.x;
    int lane = tid & 63, w = tid >> 6;
    #pragma unroll
    for (int off = 32; off > 0; off >>= 1) val += __shfl_down(val, off, 64);
    if (lane == 0) sh[w] = val;
    __syncthreads();
    int nw = blockDim.x >> 6;
    float total = 0.f;
    for (int i = 0; i < nw; i++) total += sh[i];
    __syncthreads();
    return total;
}

__device__ __forceinline__ float wave_reduce_sum(float v) {
    #pragma unroll
    for (int off = 32; off > 0; off >>= 1) v += __shfl_xor(v, off, 64);
    return v;
}

// ---- LayerNorm (ddof=1, eps on std) -> bf16, + au, av ----------------------
// One 64-lane WAVE per row: 16 f32/lane at d = lane*4 + j*256 (coalesced
// float4 per j), all reductions via shfl_xor -> ZERO __syncthreads, no LDS.
// 4 rows per 256-thread block; grid 2048.
__global__ __launch_bounds__(256) void ln_kernel(
    const float* __restrict__ ctx,
    const float* __restrict__ ln_a,
    const float* __restrict__ ln_b,
    const float* __restrict__ u,
    const float* __restrict__ v,
    unsigned short* __restrict__ xb,
    float* __restrict__ au, float* __restrict__ av) {
    int wid = threadIdx.x >> 6, lane = threadIdx.x & 63;
    int r = blockIdx.x * 4 + wid;
    const float* row = ctx + (size_t)r * D_;
    float4 x[4];
    #pragma unroll
    for (int j = 0; j < 4; j++)
        x[j] = *(const float4*)(row + lane * 4 + j * 256);
    float s = 0.f;
    #pragma unroll
    for (int j = 0; j < 4; j++) s += x[j].x + x[j].y + x[j].z + x[j].w;
    s = wave_reduce_sum(s);
    float mean = s * (1.0f / D_);
    float sq = 0.f;
    #pragma unroll
    for (int j = 0; j < 4; j++) {
        float dx = x[j].x - mean, dy = x[j].y - mean;
        float dz = x[j].z - mean, dw = x[j].w - mean;
        sq += dx * dx + dy * dy + dz * dz + dw * dw;
    }
    sq = wave_reduce_sum(sq);
    float var = sq * (1.0f / (D_ - 1));
    float inv = 1.0f / (sqrtf(var) + 1e-6f);
    float pu = 0.f, pv = 0.f;
    #pragma unroll
    for (int j = 0; j < 4; j++) {
        int d0 = lane * 4 + j * 256;
        float4 a4 = *(const float4*)(ln_a + d0);
        float4 b4 = *(const float4*)(ln_b + d0);
        float y0 = a4.x * (x[j].x - mean) * inv + b4.x;
        float y1 = a4.y * (x[j].y - mean) * inv + b4.y;
        float y2 = a4.z * (x[j].z - mean) * inv + b4.z;
        float y3 = a4.w * (x[j].w - mean) * inv + b4.w;
        ushort4 o;
        o.x = f2bf(y0); o.y = f2bf(y1); o.z = f2bf(y2); o.w = f2bf(y3);
        *(ushort4*)(xb + (size_t)r * D_ + d0) = o;
        float4 u4 = *(const float4*)(u + d0);
        float4 v4 = *(const float4*)(v + d0);
        pu += u4.x * y0 + u4.y * y1 + u4.z * y2 + u4.w * y3;
        pv += v4.x * y0 + v4.y * y1 + v4.z * y2 + v4.w * y3;
    }
    pu = wave_reduce_sum(pu);
    pv = wave_reduce_sum(pv);
    if (lane == 0) { au[r] = pu; av[r] = pv; }
}

// ---- prep: transpose-convert Wq,Wk -> bf16 AND bias terms ------------------
__global__ void prep_kernel(const float* __restrict__ Wq, const float* __restrict__ Wk,
                            const float* __restrict__ bq, const float* __restrict__ bk,
                            unsigned short* __restrict__ Wqt,
                            unsigned short* __restrict__ Wkt,
                            float* __restrict__ u, float* __restrict__ v,
                            float* __restrict__ c0) {
    int bid = blockIdx.x;
    int tid = threadIdx.x;         // 256
    if (bid < 2048) {
        __shared__ float t[32][33];
        const float* in = (bid < 1024) ? Wq : Wk;
        unsigned short* out = (bid < 1024) ? Wqt : Wkt;
        int bb = bid & 1023;
        int bx = (bb & 31) * 32, by = (bb >> 5) * 32;
        int tx = tid & 31, ty = tid >> 5;    // 32 x 8
        #pragma unroll
        for (int i = 0; i < 32; i += 8)
            t[ty + i][tx] = in[(size_t)(by + ty + i) * D_ + bx + tx];
        __syncthreads();
        #pragma unroll
        for (int i = 0; i < 32; i += 8)
            out[(size_t)(bx + ty + i) * D_ + by + tx] = f2bf(t[tx][ty + i]);
    } else {
        int b = bid - 2048;        // 0..128
        if (b == 128) {
            // c0 = sum_d bq[d]*bk[d]
            __shared__ float sh2[4];
            float p = 0.f;
            #pragma unroll
            for (int i = 0; i < 4; i++) {
                int d = tid + i * 256;
                p += bq[d] * bk[d];
            }
            float tot = block_reduce_sum(p, sh2);
            if (tid == 0) atomicAdd(c0, tot);
        } else {
            // u[c] += sum_d Wk[d][c]*bq[d]; v[c] += sum_d Wq[d][c]*bk[d]
            float ua[4] = {}, va[4] = {};
            int d0 = b * 8;
            for (int d = d0; d < d0 + 8; d++) {
                float bqd = bq[d], bkd = bk[d];
                const float* wkr = Wk + (size_t)d * D_;
                const float* wqr = Wq + (size_t)d * D_;
                #pragma unroll
                for (int i = 0; i < 4; i++) {
                    int c = tid + i * 256;
                    ua[i] += wkr[c] * bqd;
                    va[i] += wqr[c] * bkd;
                }
            }
            #pragma unroll
            for (int i = 0; i < 4; i++) {
                atomicAdd(&u[tid + i * 256], ua[i]);
                atomicAdd(&v[tid + i * 256], va[i]);
            }
        }
    }
}

// ---- MFMA bf16 GEMM 64x64 tile, 2-phase double-buffered (for Mt) -----------
// Same proven transform as gemm_fused: stage(next) -> compute(cur) -> one
// barrier. LDS 2 x (A[64][64] + B[64][64]) = 32768 B.
__global__ __launch_bounds__(256) void gemm_bt64(
    const unsigned short* __restrict__ A,
    const unsigned short* __restrict__ Bt,
    unsigned short* __restrict__ C,
    int M, int N, int K) {
    __shared__ __align__(16) unsigned short smem[16384];  // 32 KB
    const int tid = threadIdx.x;
    const int wave = tid >> 6, lane = tid & 63;
    const int bm = blockIdx.y * 64, bn = blockIdx.x * 64;
    const int lrow8 = lane >> 3;
    const int pchunk = lane & 7;
    const int m_lane = lane & 15, quad = lane >> 4;
    const int wr = wave >> 1, wc = wave & 1;

    f32x4 acc[2][2] = {};

    auto stage = [&](int buf, int k0) {
        unsigned short* As = smem + buf * 8192;
        unsigned short* Bs = As + 4096;
        #pragma unroll
        for (int c = 0; c < 2; c++) {
            int row = wave * 16 + c * 8 + lrow8;
            int gchunk = pchunk ^ (row & 7);
            const unsigned short* gpA = A + (size_t)(bm + row) * K + k0 + gchunk * 8;
            const unsigned short* gpB = Bt + (size_t)(bn + row) * K + k0 + gchunk * 8;
            __builtin_amdgcn_global_load_lds(
                (const __attribute__((address_space(1))) void*)gpA,
                (__attribute__((address_space(3))) void*)(As + (wave * 16 + c * 8) * 64),
                16, 0, 0);
            __builtin_amdgcn_global_load_lds(
                (const __attribute__((address_space(1))) void*)gpB,
                (__attribute__((address_space(3))) void*)(Bs + (wave * 16 + c * 8) * 64),
                16, 0, 0);
        }
    };

    const int nt = K >> 6;
    stage(0, 0);
    __syncthreads();
    int cur = 0;
    for (int t = 0; t < nt; ++t) {
        if (t < nt - 1) stage(cur ^ 1, (t + 1) * 64);
        const unsigned short* As = smem + cur * 8192;
        const unsigned short* Bs = As + 4096;
        #pragma unroll
        for (int kk = 0; kk < 2; kk++) {
            bf16x8 af[2], bfr[2];
            #pragma unroll
            for (int i = 0; i < 2; i++) {
                int row = wr * 32 + i * 16 + m_lane;
                int lchunk = kk * 4 + quad;
                af[i] = *(const bf16x8*)(As + row * 64 + (lchunk ^ (row & 7)) * 8);
            }
            #pragma unroll
            for (int j = 0; j < 2; j++) {
                int row = wc * 32 + j * 16 + m_lane;
                int lchunk = kk * 4 + quad;
                bfr[j] = *(const bf16x8*)(Bs + row * 64 + (lchunk ^ (row & 7)) * 8);
            }
            #pragma unroll
            for (int i = 0; i < 2; i++)
                #pragma unroll
                for (int j = 0; j < 2; j++)
                    acc[i][j] = __builtin_amdgcn_mfma_f32_16x16x32_bf16(
                        af[i], bfr[j], acc[i][j], 0, 0, 0);
        }
        __syncthreads();
        cur ^= 1;
    }
    #pragma unroll
    for (int i = 0; i < 2; i++)
        #pragma unroll
        for (int j = 0; j < 2; j++)
            #pragma unroll
            for (int r = 0; r < 4; r++) {
                int row = bm + wr * 32 + i * 16 + quad * 4 + r;
                int col = bn + wc * 32 + j * 16 + m_lane;
                C[(size_t)row * N + col] = f2bf(acc[i][j][r]);
            }
}

// ---- MFMA GEMM 128x128 tile, 2-PHASE double-buffered pipeline --------------
// (measured R7: dropped gemm_fused below the 41us harness fills; frozen)
__device__ __forceinline__ int xs_idx(int row, int col) {
    return row * 128 + (((col >> 3) ^ (row & 7)) << 3) + (col & 7);
}

__global__ __launch_bounds__(256) void gemm_fused(
    const unsigned short* __restrict__ A,   // Xb [BS][D]
    const unsigned short* __restrict__ Bt,  // Mt [D][D]
    float* __restrict__ ydu, float* __restrict__ ydd,
    int M, int N, int K) {
    __shared__ __align__(16) unsigned short smem[32768];  // 65536 B
    const int tid = threadIdx.x;
    const int wave = tid >> 6, lane = tid & 63;
    const int bid = blockIdx.x;
    const int bm = (bid & 63) * 128, bn = (bid >> 6) * 128;
    const int lrow8 = lane >> 3;             // 0..7
    const int pchunk = lane & 7;
    const int m_lane = lane & 15, quad = lane >> 4;
    const int wr = wave >> 1, wc = wave & 1; // wave's 64x64 quadrant

    f32x4 acc[4][4] = {};                    // rows wr*64+i*16, cols wc*64+j*16

    auto stage = [&](int buf, int k0) {
        unsigned short* As = smem + buf * 16384;
        unsigned short* Bs = As + 8192;
        #pragma unroll
        for (int c = 0; c < 4; c++) {
            int row = wave * 32 + c * 8 + lrow8;
            int gchunk = pchunk ^ (row & 7);
            const unsigned short* gpA = A + (size_t)(bm + row) * K + k0 + gchunk * 8;
            __builtin_amdgcn_global_load_lds(
                (const __attribute__((address_space(1))) void*)gpA,
                (__attribute__((address_space(3))) void*)(As + (wave * 32 + c * 8) * 64),
                16, 0, 0);
            const unsigned short* gpB = Bt + (size_t)(bn + row) * K + k0 + gchunk * 8;
            __builtin_amdgcn_global_load_lds(
                (const __attribute__((address_space(1))) void*)gpB,
                (__attribute__((address_space(3))) void*)(Bs + (wave * 32 + c * 8) * 64),
                16, 0, 0);
        }
    };

    const int nt = K >> 6;                   // 16 K-steps
    stage(0, 0);
    __syncthreads();                          // drain prologue loads
    int cur = 0;
    for (int t = 0; t < nt; ++t) {
        if (t < nt - 1) stage(cur ^ 1, (t + 1) * 64);   // prefetch next tile
        const unsigned short* As = smem + cur * 16384;
        const unsigned short* Bs = As + 8192;
        #pragma unroll
        for (int kk = 0; kk < 2; kk++) {
            bf16x8 af[4], bfr[4];
            #pragma unroll
            for (int i = 0; i < 4; i++) {
                int row = wr * 64 + i * 16 + m_lane;
                int lchunk = kk * 4 + quad;
                af[i] = *(const bf16x8*)(As + row * 64 + (lchunk ^ (row & 7)) * 8);
            }
            #pragma unroll
            for (int j = 0; j < 4; j++) {
                int row = wc * 64 + j * 16 + m_lane;
                int lchunk = kk * 4 + quad;
                bfr[j] = *(const bf16x8*)(Bs + row * 64 + (lchunk ^ (row & 7)) * 8);
            }
            #pragma unroll
            for (int i = 0; i < 4; i++)
                #pragma unroll
                for (int j = 0; j < 4; j++)
                    acc[i][j] = __builtin_amdgcn_mfma_f32_16x16x32_bf16(
                        af[i], bfr[j], acc[i][j], 0, 0, 0);
        }
        __syncthreads();   // vmcnt(0)+lgkmcnt(0)+barrier: next buf ready, cur buf free
        cur ^= 1;
    }

    // ---- epilogue: stage X tile [128][128] via global_load_lds -------------
    unsigned short* Xs = smem;               // [128][128] linear u16 = 32 KB
    #pragma unroll
    for (int it = 0; it < 8; it++) {
        int c = it * 256 + wave * 64 + lane; // chunk id, 2048 total
        int lr = c >> 4;                     // 0..127
        int ch = c & 15;                     // 0..15
        int gch = ch ^ (lr & 7);             // source swizzle (involution)
        const unsigned short* gp = A + (size_t)(bm + lr) * K + bn + gch * 8;
        __builtin_amdgcn_global_load_lds(
            (const __attribute__((address_space(1))) void*)gp,
            (__attribute__((address_space(3))) void*)(Xs + (size_t)(it * 256 + wave * 64) * 8),
            16, 0, 0);
    }
    __syncthreads();

    #pragma unroll
    for (int i = 0; i < 4; i++) {
        #pragma unroll
        for (int r = 0; r < 4; r++) {
            int lrow = wr * 64 + i * 16 + quad * 4 + r;   // 0..127
            int row = bm + lrow;
            int s = row & (S_ - 1);
            bool hu = (s < S_ - 1), hd = (s > 0);
            float pu = 0.f, pd = 0.f;
            #pragma unroll
            for (int j = 0; j < 4; j++) {
                int lc = wc * 64 + j * 16 + m_lane;
                float a = acc[i][j][r];
                if (hu) {
                    float xu = (lrow < 127) ? bf2f(Xs[xs_idx(lrow + 1, lc)])
                                            : bf2f(A[(size_t)(row + 1) * K + bn + lc]);
                    pu += a * xu;
                }
                if (hd) {
                    float xd = (lrow > 0) ? bf2f(Xs[xs_idx(lrow - 1, lc)])
                                          : bf2f(A[(size_t)(row - 1) * K + bn + lc]);
                    pd += a * xd;
                }
            }
            #pragma unroll
            for (int off = 1; off < 16; off <<= 1) {
                pu += __shfl_xor(pu, off, 64);
                pd += __shfl_xor(pd, off, 64);
            }
            if (m_lane == 0) {
                atomicAdd(&ydu[row], pu);
                atomicAdd(&ydd[row], pd);
            }
        }
    }
}

// ---- fused banded softmax + f64 prefix scan --------------------------------
__global__ void softmax_prefix(const float* __restrict__ ydu, const float* __restrict__ ydd,
                               const float* __restrict__ au, const float* __restrict__ av,
                               const float* __restrict__ c0p, const int* __restrict__ eos,
                               float* __restrict__ Pup, float* __restrict__ Pdn,
                               float* __restrict__ bg, double* __restrict__ C) {
    __shared__ float pdsh[1024];
    __shared__ double wsum[16];
    int b = blockIdx.x;
    int t = threadIdx.x;           // 0..1023 = row s
    int r = b * S_ + t;
    float c0 = *c0p;
    const float inv_d = 1.0f / D_;
    bool mu = false, md = false;
    float su = 0.f, sd = 0.f;
    if (t < S_ - 1) {
        mu = eos[(size_t)b * S_ * S_ + (size_t)t * S_ + (t + 1)] != 0;
        su = (ydu[r] + av[r] + au[r + 1] + c0) * inv_d;
    }
    if (t > 0) {
        md = eos[(size_t)b * S_ * S_ + (size_t)t * S_ + (t - 1)] != 0;
        sd = (ydd[r] + av[r] + au[r - 1] + c0) * inv_d;
    }
    float pu, pd, pb;
    if (mu && md) {
        float m = fmaxf(su, sd);
        float eu = expf(su - m), ed = expf(sd - m);
        float inv = 1.0f / (eu + ed);
        pu = eu * inv; pd = ed * inv; pb = 0.f;
    } else if (mu) { pu = 1.f; pd = 0.f; pb = 0.f; }
    else if (md)   { pu = 0.f; pd = 1.f; pb = 0.f; }
    else           { pu = pd = pb = 1.0f / S_; }
    Pup[r] = pu; Pdn[r] = pd; bg[r] = pb;
    pdsh[t] = pd;
    __syncthreads();
    double l = 0.0;
    if (t < S_ - 1) {
        float p = sqrtf(pu * pdsh[t + 1] + 1e-9f) + 1e-9f;
        l = log((double)p);
    }
    int lane = t & 63, w = t >> 6;
    double vv = l;
    #pragma unroll
    for (int off = 1; off < 64; off <<= 1) {
        double o = __shfl_up(vv, off, 64);
        if (lane >= off) vv += o;
    }
    if (lane == 63) wsum[w] = vv;
    __syncthreads();
    if (t == 0) {
        double acc = 0.0;
        #pragma unroll
        for (int i = 0; i < 16; i++) { double x = wsum[i]; wsum[i] = acc; acc += x; }
    }
    __syncthreads();
    vv += wsum[w];
    size_t base = (size_t)b * S_;
    if (t == 0) C[base] = 0.0;
    if (t < S_ - 1) C[base + t + 1] = vv;
}

// ---- final outputs: g and neibor -------------------------------------------
__global__ void write_out(const float* __restrict__ Pup, const float* __restrict__ Pdn,
                          const float* __restrict__ bg, const double* __restrict__ C,
                          float* __restrict__ out) {
    int r = blockIdx.x;
    int b = r >> 10, s = r & (S_ - 1);
    size_t rowbase = (size_t)r * S_;
    size_t bb = (size_t)b * S_;
    float pu_s = (s < S_ - 1) ? Pup[r] : 0.f;
    float pd_s = (s > 0) ? Pdn[r] : 0.f;
    float bg_s = bg[r];
    double C_s = C[r];
    int t0 = threadIdx.x * 4;
    float* gp = out;
    float* np = out + (size_t)B_ * S_ * S_;
    float4 bgv = *(const float4*)(bg + bb + t0);
    float4 gv, nv;
    #pragma unroll
    for (int j = 0; j < 4; j++) {
        int t = t0 + j;
        float P_st = (t == s + 1) ? pu_s : ((t == s - 1) ? pd_s : bg_s);
        float P_ts;
        if (t == s - 1)      P_ts = Pup[bb + t];
        else if (t == s + 1) P_ts = Pdn[bb + t];
        else                 P_ts = ((const float*)&bgv)[j];
        float neib = sqrtf(P_st * P_ts + 1e-9f);
        float g;
        if (t == s) {
            g = neib;
        } else {
            double diff = (t > s) ? (C[bb + t] - C_s) : (C_s - C[bb + t]);
            g = expf((float)diff) + 1e-9f;
        }
        ((float*)&gv)[j] = g;
        ((float*)&nv)[j] = neib;
    }
    *(float4*)(gp + rowbase + t0) = gv;
    *(float4*)(np + rowbase + t0) = nv;
}

// ---- launcher ---------------------------------------------------------------
extern "C" void kernel_launch(void* const* d_in, const int* in_sizes, int n_in,
                              void* d_out, int out_size, void* d_ws, size_t ws_size,
                              hipStream_t stream) {
    const float* ctx  = (const float*)d_in[0];
    const int*   eos  = (const int*)d_in[1];
    const float* Wq   = (const float*)d_in[2];
    const float* bq   = (const float*)d_in[3];
    const float* Wk   = (const float*)d_in[4];
    const float* bk   = (const float*)d_in[5];
    const float* ln_a = (const float*)d_in[6];
    const float* ln_b = (const float*)d_in[7];
    float* out = (float*)d_out;

    char* ws = (char*)d_ws;
    size_t off = 0;
    auto alloc = [&](size_t bytes) {
        void* p = ws + off;
        off += (bytes + 255) & ~(size_t)255;
        return p;
    };
    unsigned short* Xb  = (unsigned short*)alloc((size_t)BS * D_ * 2);
    unsigned short* Wqt = (unsigned short*)alloc((size_t)D_ * D_ * 2);
    unsigned short* Wkt = (unsigned short*)alloc((size_t)D_ * D_ * 2);
    unsigned short* Mt  = (unsigned short*)alloc((size_t)D_ * D_ * 2);
    // ---- zeroed region (contiguous): ydu, ydd, u, v, c0 ----
    float*  ydu = (float*)alloc(BS * 4);
    float*  ydd = (float*)alloc(BS * 4);
    float*  u   = (float*)alloc(D_ * 4);
    float*  v   = (float*)alloc(D_ * 4);
    float*  c0  = (float*)alloc(4);
    size_t zero_bytes = (size_t)((char*)c0 - (char*)ydu) + 256;
    // ---- rest (written, not accumulated) ----
    float*  au  = (float*)alloc(BS * 4);
    float*  av  = (float*)alloc(BS * 4);
    float*  Pup = (float*)alloc(BS * 4);
    float*  Pdn = (float*)alloc(BS * 4);
    float*  bg  = (float*)alloc(BS * 4);
    double* Cp  = (double*)alloc(BS * 8);

    // 0. zero the atomic-accumulate targets
    hipMemsetAsync(ydu, 0, zero_bytes, stream);
    // 1. prep: transpose Wq/Wk -> bf16, bias terms u, v (128 blocks), c0
    prep_kernel<<<2177, 256, 0, stream>>>(Wq, Wk, bq, bk, Wqt, Wkt, u, v, c0);
    // 2. LayerNorm -> bf16 (+ au, av), wave-per-row
    ln_kernel<<<BS / 4, 256, 0, stream>>>(ctx, ln_a, ln_b, u, v, Xb, au, av);
    // 3. Mt[n][k] = sum_d Wk[d][n] Wq[d][k], 2-phase pipelined
    gemm_bt64<<<dim3(16, 16), 256, 0, stream>>>(Wkt, Wqt, Mt, D_, D_, D_);
    // 4. fused: Y = Xb Mt^T + banded dots, 2-phase pipeline, XCD-swizzled grid
    gemm_fused<<<512, 256, 0, stream>>>(Xb, Mt, ydu, ydd, BS, D_, D_);
    // 5. fused banded softmax + prefix scan
    softmax_prefix<<<B_, 1024, 0, stream>>>(ydu, ydd, au, av, c0, eos, Pup, Pdn, bg, Cp);
    // 6. outputs
    write_out<<<BS, 256, 0, stream>>>(Pup, Pdn, bg, Cp, out);
}